// Round 7
// baseline (276.703 us; speedup 1.0000x reference)
//
#include <hip/hip_runtime.h>

// KPN per-pixel dynamic kernel conv.
// data:    [1, 8, 3, 96, 96]        fp32 (~0.9 MB, cached)
// kernels: [1, 8, 225, 3, 96, 96]   fp32 (199 MB, read exactly once)
// out:     [1, 8, 3, 96, 96]        fp32
// out[t,c,h,w] = sum_{i,j} kernels[t,i*15+j,c,h,w] * data[t,c,h+i-7,w+j-7] (zero pad)
//
// Round 7: the timed replay's caches are 100% dirty (796 MB 0xAA poison fill
// precedes every launch), so every allocating read of the 199 MB stream forces
// a dirty write-back (~2x effective traffic). Switch the kernel stream to raw
// buffer loads with cache policy SC0|NT|SC1 (0x13): SC1 -> L2 bypass on
// gfx940+, NT -> non-temporal at L3/MALL. No allocation -> no forced
// write-backs. Structure otherwise = round 6 (fused, 864 one-wave blocks,
// double-buffered tap rows). No LDS / barriers / atomics -> deterministic.

typedef float vf4 __attribute__((ext_vector_type(4)));
typedef int   v4i __attribute__((ext_vector_type(4)));

constexpr int K  = 15;
constexpr int P  = 7;
constexpr int H  = 96;
constexpr int W  = 96;
constexpr int C  = 3;
constexpr int T  = 8;
constexpr int HW = H * W;              // 9216
constexpr int K2 = K * K;              // 225
constexpr int NP = T * C;              // 24 planes
constexpr int NE = NP * HW;            // 221184 output elems
constexpr int CHW = C * HW;            // 27648 floats between consecutive taps
constexpr int NQ   = NE / 4;           // 55296 quads
constexpr int BLK  = 64;               // one wave per block
constexpr int NBLK = NQ / BLK;         // 864 blocks
constexpr unsigned KBYTES = (unsigned)T * K2 * C * HW * 4u;  // 199,065,600

#if __has_builtin(__builtin_amdgcn_raw_buffer_load_v4f32)
#define USE_BUFFER_STREAM 1
#else
#define USE_BUFFER_STREAM 0
#endif

__device__ __forceinline__ vf4 stream_load(v4i rsrc, const float* base, int voff_bytes) {
#if USE_BUFFER_STREAM
    // aux = SC0(1) | NT(2) | SC1(16): system-scope non-temporal read.
    return __builtin_amdgcn_raw_buffer_load_v4f32(rsrc, voff_bytes, 0, 0x13);
#else
    return __builtin_nontemporal_load(
        reinterpret_cast<const vf4*>(reinterpret_cast<const char*>(base) + voff_bytes));
#endif
}

__global__ __launch_bounds__(BLK) void kpn_fused_stream(
    const float* __restrict__ data,
    const float* __restrict__ kern,
    float* __restrict__ out)
{
    const int q     = blockIdx.x * BLK + threadIdx.x;   // quad id
    const int w4    = q % (W / 4);
    const int rem   = q / (W / 4);
    const int h     = rem % H;
    const int plane = rem / H;          // t*C + c
    const int t     = plane / C;
    const int c     = plane % C;
    const int col   = w4 * 4;

    // SRD for the kernels tensor (stride 0, raw dword access).
    const unsigned long long kb = (unsigned long long)kern;
    v4i rsrc;
    rsrc.x = (int)(unsigned)kb;
    rsrc.y = (int)(unsigned)(kb >> 32);        // high bits + stride=0
    rsrc.z = (int)KBYTES;                      // num_records (bytes)
    rsrc.w = 0x00020000;                       // raw dword buffer

    // tap (i*K+j) byte offset = 4 * (kofs0 + (i*K+j)*CHW)
    const int kofs0 = ((t * K2) * C + c) * HW + h * W + col;
    const float* __restrict__ dpl = data + plane * HW;

    // Column clamp/validity is row-independent: precompute once.
    int  colc[K + 3];
    bool cval[K + 3];
    #pragma unroll
    for (int m = 0; m < K + 3; ++m) {
        const int cc = col - P + m;
        cval[m] = (cc >= 0) && (cc < W);
        colc[m] = (cc < 0) ? 0 : ((cc >= W) ? (W - 1) : cc);
    }

    float acc[4] = {0.f, 0.f, 0.f, 0.f};

    auto load_row = [&](vf4 (&buf)[K], int i) {
        const int base = (kofs0 + i * K * CHW) * 4;
        #pragma unroll
        for (int j = 0; j < K; ++j)
            buf[j] = stream_load(rsrc, kern, base + j * (CHW * 4));
    };

    auto consume_row = [&](vf4 (&buf)[K], int i) {
        const int srow = h + i - P;
        const bool rv  = (srow >= 0) && (srow < H);
        const float* __restrict__ drow = dpl + (rv ? srow : 0) * W;
        float dwin[K + 3];
        #pragma unroll
        for (int m = 0; m < K + 3; ++m) {
            const float v = drow[colc[m]];           // address always in-bounds
            dwin[m] = (rv && cval[m]) ? v : 0.f;
        }
        #pragma unroll
        for (int j = 0; j < K; ++j) {
            acc[0] += buf[j][0] * dwin[j + 0];
            acc[1] += buf[j][1] * dwin[j + 1];
            acc[2] += buf[j][2] * dwin[j + 2];
            acc[3] += buf[j][3] * dwin[j + 3];
        }
    };

    vf4 A[K], B[K];
    load_row(A, 0);
    #pragma unroll 1
    for (int i = 0; i < K - 1; i += 2) {     // i = 0,2,...,12
        load_row(B, i + 1);
        consume_row(A, i);
        load_row(A, i + 2);                  // i+2 <= 14: always a valid row
        consume_row(B, i + 1);
    }
    consume_row(A, K - 1);

    vf4 o = { acc[0], acc[1], acc[2], acc[3] };
    float* op = out + (size_t)plane * HW + (size_t)h * W + col;
    __builtin_nontemporal_store(o, reinterpret_cast<vf4*>(op));
}

extern "C" void kernel_launch(void* const* d_in, const int* in_sizes, int n_in,
                              void* d_out, int out_size, void* d_ws, size_t ws_size,
                              hipStream_t stream) {
    const float* data = (const float*)d_in[0];
    const float* kern = (const float*)d_in[1];
    float* out        = (float*)d_out;
    hipLaunchKernelGGL(kpn_fused_stream, dim3(NBLK), dim3(BLK), 0, stream,
                       data, kern, out);
}